// Round 4
// baseline (570.698 us; speedup 1.0000x reference)
//
#include <hip/hip_runtime.h>

#define TE 64          // edges per tile
#define THREADS 256    // 4 waves
#define GRID 512       // persistent: 2 blocks/CU x 256 CUs exactly
#define XS 136         // u16 stride per edge row: 128 + 8 pad (272 B, 16B-aligned, 2-way banks)
#define T_SM 0.05f
#define NEAR_MARGIN 1e-3f

typedef short s8v __attribute__((ext_vector_type(8)));    // 8 bf16 = 4 VGPRs (MFMA A/B frag)
typedef float f16v __attribute__((ext_vector_type(16)));  // 32x32 C/D frag
typedef unsigned short u16;

__device__ __forceinline__ u16 f2bf(float x) {            // fp32 -> bf16 RNE
    union { float f; unsigned u; } v; v.f = x;
    return (u16)((v.u + 0x7FFFu + ((v.u >> 16) & 1u)) >> 16);
}
__device__ __forceinline__ float bf2f(u16 h) {
    union { unsigned u; float f; } v; v.u = ((unsigned)h) << 16;
    return v.f;
}

// ---- kernel 1: W1 [256,256] f32 -> bf16 hi/lo in B-fragment layout ----
// col n, k-group g=k/8: w1t[n*512 + g*16 + j] = hi, [+8] = lo. Works for both
// 16x16x32 (g = half*16+4s+q) and 32x32x16 (g = half*16+2*sl+q8) fragment reads.
__global__ void prep_kernel(const float* __restrict__ W1, u16* __restrict__ w1t,
                            int* __restrict__ count) {
    int t = blockIdx.x * 256 + threadIdx.x;
    if (t == 0) *count = 0;
    if (t < 65536) {
        int n = t & 255, k = t >> 8;
        float w = W1[k * 256 + n];
        u16 h = f2bf(w);
        u16 l = f2bf(w - bf2f(h));
        int g = k >> 3, j = k & 7;
        w1t[n * 512 + g * 16 + j] = h;
        w1t[n * 512 + g * 16 + j + 8] = l;
    }
}

// ---- kernel 2: persistent fused gather + split-bf16 32x32x16 MFMA + epilogue ----
// wave wv owns cols [wv*64, wv*64+64) as 2 n-tiles of 32; edges 64 = 2 m-tiles of 32.
// A[m=lane&31][k=8*(lane>>5)+j]; B[k][n=lane&31] mirrored;
// C/D: col=lane&31, row=(reg&3)+8*(reg>>2)+4*(lane>>5)   (m74/m101-verified).
__global__ __launch_bounds__(THREADS, 2)   // 256-VGPR cap: R3's spill (WRITE 124MB) must not recur
void linkmlp_mfma(const float* __restrict__ emb, const int* __restrict__ ei,
                  const u16* __restrict__ w1t, const float* __restrict__ b1,
                  const float* __restrict__ W2, const float* __restrict__ b2p,
                  float* __restrict__ out, int* __restrict__ count,
                  int* __restrict__ list, int cap, int E)
{
    __shared__ u16 x_hi[2][TE * XS];   // double-buffered x tiles (hi/lo bf16)
    __shared__ u16 x_lo[2][TE * XS];
    __shared__ float red[4][TE];

    const int tid  = threadIdx.x;
    const int lane = tid & 63;
    const int wv   = tid >> 6;
    const int l31  = lane & 31;
    const int q8   = lane >> 5;
    const int ge   = tid >> 5;    // gather: edge sub-index 0..7 (+8 per pass)
    const int gseg = tid & 31;    // gather: float4 segment within 512B row

    const int ntiles = (E + TE - 1) / TE;
    if ((int)blockIdx.x >= ntiles) return;
    const int nb = (ntiles - blockIdx.x + GRID - 1) / GRID;
    const int H  = 2 * nb;        // halves: even=row endpoint, odd=col endpoint

    float b1v[2], w2v[2];
    #pragma unroll
    for (int nt = 0; nt < 2; ++nt) {
        int c = wv * 64 + nt * 32 + l31;
        b1v[nt] = b1[c];
        w2v[nt] = W2[c];
    }
    const float b2s = b2p[0];

    f16v acc[2][2];
    #pragma unroll
    for (int mt = 0; mt < 2; ++mt)
        #pragma unroll
        for (int nt = 0; nt < 2; ++nt)
            acc[mt][nt] = (f16v)0.f;

    float4 gv[8];
    auto issue_gather = [&](int hs) {          // 8 independent float4 loads (random rows)
        const int tile = blockIdx.x + (hs >> 1) * GRID;
        const int half = hs & 1;
        const int base = tile * TE;
        #pragma unroll
        for (int q = 0; q < 8; ++q) {
            int e = base + ge + 8 * q;
            int node = ei[(size_t)half * E + (e < E ? e : 0)];
            gv[q] = ((const float4*)(emb + (size_t)node * 128))[gseg];
        }
    };
    auto write_gather = [&](int p) {           // split fp32 -> bf16 hi/lo, ds_write_b64 x2
        #pragma unroll
        for (int q = 0; q < 8; ++q) {
            float4 v = gv[q];
            u16 h0 = f2bf(v.x), h1 = f2bf(v.y), h2 = f2bf(v.z), h3 = f2bf(v.w);
            u16 l0 = f2bf(v.x - bf2f(h0)), l1 = f2bf(v.y - bf2f(h1));
            u16 l2 = f2bf(v.z - bf2f(h2)), l3 = f2bf(v.w - bf2f(h3));
            int off = (ge + 8 * q) * XS + gseg * 4;
            *(uint2*)&x_hi[p][off] = make_uint2((unsigned)h0 | ((unsigned)h1 << 16),
                                                (unsigned)h2 | ((unsigned)h3 << 16));
            *(uint2*)&x_lo[p][off] = make_uint2((unsigned)l0 | ((unsigned)l1 << 16),
                                                (unsigned)l2 | ((unsigned)l3 << 16));
        }
    };

    // prologue: stage half 0 into buffer 0
    issue_gather(0);
    write_gather(0);
    __syncthreads();

    for (int hs = 0; hs < H; ++hs) {
        const int p    = hs & 1;               // compute buffer parity (== half parity)
        const int half = hs & 1;
        const int base = (blockIdx.x + (hs >> 1) * GRID) * TE;

        const int arow0 = l31 * XS;
        const int arow1 = (32 + l31) * XS;
        const u16* bbase0 = w1t + (size_t)(wv * 64 + l31) * 512 + (half * 16 + q8) * 16;
        const u16* bbase1 = bbase0 + 32 * 512;

        auto kstep = [&](int sl) {             // one K=16 step: 4 ds_read_b128 + 4 glb x4 + 12 MFMA
            const int aoff = 16 * sl + 8 * q8;
            s8v ah0 = *(const s8v*)&x_hi[p][arow0 + aoff];
            s8v ah1 = *(const s8v*)&x_hi[p][arow1 + aoff];
            s8v al0 = *(const s8v*)&x_lo[p][arow0 + aoff];
            s8v al1 = *(const s8v*)&x_lo[p][arow1 + aoff];
            const u16* bp0 = bbase0 + sl * 32;
            const u16* bp1 = bbase1 + sl * 32;
            s8v bh0 = *(const s8v*)bp0;  s8v bl0 = *(const s8v*)(bp0 + 8);
            s8v bh1 = *(const s8v*)bp1;  s8v bl1 = *(const s8v*)(bp1 + 8);
            // 3-term split: xh*wh + xh*wl + xl*wh (xl*wl ~2^-18, dropped)
            acc[0][0] = __builtin_amdgcn_mfma_f32_32x32x16_bf16(ah0, bh0, acc[0][0], 0, 0, 0);
            acc[0][0] = __builtin_amdgcn_mfma_f32_32x32x16_bf16(ah0, bl0, acc[0][0], 0, 0, 0);
            acc[0][0] = __builtin_amdgcn_mfma_f32_32x32x16_bf16(al0, bh0, acc[0][0], 0, 0, 0);
            acc[1][0] = __builtin_amdgcn_mfma_f32_32x32x16_bf16(ah1, bh0, acc[1][0], 0, 0, 0);
            acc[1][0] = __builtin_amdgcn_mfma_f32_32x32x16_bf16(ah1, bl0, acc[1][0], 0, 0, 0);
            acc[1][0] = __builtin_amdgcn_mfma_f32_32x32x16_bf16(al1, bh0, acc[1][0], 0, 0, 0);
            acc[0][1] = __builtin_amdgcn_mfma_f32_32x32x16_bf16(ah0, bh1, acc[0][1], 0, 0, 0);
            acc[0][1] = __builtin_amdgcn_mfma_f32_32x32x16_bf16(ah0, bl1, acc[0][1], 0, 0, 0);
            acc[0][1] = __builtin_amdgcn_mfma_f32_32x32x16_bf16(al0, bh1, acc[0][1], 0, 0, 0);
            acc[1][1] = __builtin_amdgcn_mfma_f32_32x32x16_bf16(ah1, bh1, acc[1][1], 0, 0, 0);
            acc[1][1] = __builtin_amdgcn_mfma_f32_32x32x16_bf16(ah1, bl1, acc[1][1], 0, 0, 0);
            acc[1][1] = __builtin_amdgcn_mfma_f32_32x32x16_bf16(al1, bh1, acc[1][1], 0, 0, 0);
        };

        kstep(0); kstep(1); kstep(2); kstep(3);
        if (hs + 1 < H) issue_gather(hs + 1);  // prefetch next half under remaining MFMAs
        kstep(4); kstep(5); kstep(6); kstep(7);
        if (hs + 1 < H) write_gather(1 - p);

        if (half == 1) {
            // epilogue: h=relu(acc+b1), partial = sum over this wave's 64 cols
            #pragma unroll
            for (int mt = 0; mt < 2; ++mt) {
                #pragma unroll
                for (int r = 0; r < 16; ++r) {
                    float h0 = acc[mt][0][r] + b1v[0];
                    float h1 = acc[mt][1][r] + b1v[1];
                    float pp = (h0 > 0.f ? h0 : 0.f) * w2v[0] + (h1 > 0.f ? h1 : 0.f) * w2v[1];
                    pp += __shfl_xor(pp, 1);  pp += __shfl_xor(pp, 2);
                    pp += __shfl_xor(pp, 4);  pp += __shfl_xor(pp, 8);
                    pp += __shfl_xor(pp, 16);
                    if (l31 == 0)
                        red[wv][mt * 32 + (r & 3) + 8 * (r >> 2) + 4 * q8] = pp;
                }
            }
        }
        __syncthreads();   // x-buffer protection + red visibility

        if (half == 1) {
            if (tid < TE) {
                int eg = base + tid;
                if (eg < E) {
                    float raw = red[0][tid] + red[1][tid] + red[2][tid] + red[3][tid] + b2s;
                    out[eg] = (raw < T_SM) ? 0.f : raw;
                    if (fabsf(raw - T_SM) < NEAR_MARGIN) {   // near-threshold -> exact recompute
                        int pos = atomicAdd(count, 1);
                        if (pos < cap) list[pos] = eg;
                    }
                }
            }
            #pragma unroll
            for (int mt = 0; mt < 2; ++mt)
                #pragma unroll
                for (int nt = 0; nt < 2; ++nt)
                    acc[mt][nt] = (f16v)0.f;
        }
    }
}

// ---- kernel 3: exact fp32 recompute of near-threshold edges (one wave/edge) ----
__global__ __launch_bounds__(256, 4)
void fixup_kernel(const float* __restrict__ emb, const int* __restrict__ ei,
                  const float* __restrict__ W1, const float* __restrict__ b1,
                  const float* __restrict__ W2, const float* __restrict__ b2p,
                  const int* __restrict__ count, const int* __restrict__ list,
                  float* __restrict__ out, int E, int cap)
{
    int cnt = *count; if (cnt > cap) cnt = cap;
    const int lane = threadIdx.x & 63;
    const int gw = (blockIdx.x * 256 + threadIdx.x) >> 6;
    const int nw = (gridDim.x * 256) >> 6;
    for (int i = gw; i < cnt; i += nw) {
        int e = list[i];
        int rn = ei[e], cn = ei[E + e];
        const float* src = (lane < 32) ? emb + (size_t)rn * 128 + lane * 4
                                       : emb + (size_t)cn * 128 + (lane - 32) * 4;
        float4 xv = *(const float4*)src;
        float hacc[4] = {0.f, 0.f, 0.f, 0.f};
        for (int k0 = 0; k0 < 256; k0 += 4) {
            int sl = k0 >> 2;
            float x0 = __shfl(xv.x, sl), x1 = __shfl(xv.y, sl);
            float x2 = __shfl(xv.z, sl), x3 = __shfl(xv.w, sl);
            #pragma unroll
            for (int c = 0; c < 4; ++c) {
                int col = lane + 64 * c;
                hacc[c] += x0 * W1[(k0 + 0) * 256 + col] + x1 * W1[(k0 + 1) * 256 + col]
                         + x2 * W1[(k0 + 2) * 256 + col] + x3 * W1[(k0 + 3) * 256 + col];
            }
        }
        float p = 0.f;
        #pragma unroll
        for (int c = 0; c < 4; ++c) {
            float h = hacc[c] + b1[lane + 64 * c];
            p += (h > 0.f ? h : 0.f) * W2[lane + 64 * c];
        }
        p += __shfl_xor(p, 1);  p += __shfl_xor(p, 2);  p += __shfl_xor(p, 4);
        p += __shfl_xor(p, 8);  p += __shfl_xor(p, 16); p += __shfl_xor(p, 32);
        if (lane == 0) {
            float raw = p + b2p[0];
            out[e] = (raw < T_SM) ? 0.f : raw;
        }
    }
}

extern "C" void kernel_launch(void* const* d_in, const int* in_sizes, int n_in,
                              void* d_out, int out_size, void* d_ws, size_t ws_size,
                              hipStream_t stream) {
    const float* emb = (const float*)d_in[0];
    const int*   ei  = (const int*)  d_in[1];
    const float* W1  = (const float*)d_in[2];
    const float* b1  = (const float*)d_in[3];
    const float* W2  = (const float*)d_in[4];
    const float* b2  = (const float*)d_in[5];
    float* out = (float*)d_out;
    const int E = out_size;

    // ws layout: [0,256KB) w1t ; [256KB] count ; [256KB+64 ..) fixup list
    u16* w1t   = (u16*)d_ws;
    int* count = (int*)((char*)d_ws + 262144);
    int* list  = (int*)((char*)d_ws + 262208);
    long avail = (long)ws_size - 262208;
    int cap = (avail > 4) ? (int)(avail / 4) : 0;
    if (cap > E) cap = E;

    hipLaunchKernelGGL(prep_kernel, dim3(256), dim3(256), 0, stream, W1, w1t, count);
    hipLaunchKernelGGL(linkmlp_mfma, dim3(GRID), dim3(THREADS), 0, stream,
                       emb, ei, w1t, b1, W2, b2, out, count, list, cap, E);
    hipLaunchKernelGGL(fixup_kernel, dim3(128), dim3(256), 0, stream,
                       emb, ei, W1, b1, W2, b2, count, list, out, E, cap);
}

// Round 5
// 474.822 us; speedup vs baseline: 1.2019x; 1.2019x over previous
//
#include <hip/hip_runtime.h>

#define TE 64          // edges per tile/block
#define THREADS 256    // 4 waves
#define XS 136         // u16 stride per edge row: 128 + 8 pad
#define T_SM 0.05f
#define NEAR_MARGIN 1e-3f

typedef short s8v __attribute__((ext_vector_type(8)));    // 8 bf16 = 4 VGPRs (MFMA A/B frag)
typedef float f16v __attribute__((ext_vector_type(16)));  // 32x32 C/D frag
typedef unsigned short u16;

__device__ __forceinline__ u16 f2bf(float x) {            // fp32 -> bf16 RNE
    union { float f; unsigned u; } v; v.f = x;
    return (u16)((v.u + 0x7FFFu + ((v.u >> 16) & 1u)) >> 16);
}
__device__ __forceinline__ float bf2f(u16 h) {
    union { unsigned u; float f; } v; v.u = ((unsigned)h) << 16;
    return v.f;
}

// ---- kernel 1: W1 [256,256] f32 -> bf16 hi/lo in B-fragment layout ----
// col n, k-group g=k/8: w1t[n*512 + g*16 + j] = hi, [+8] = lo.
__global__ void prep_kernel(const float* __restrict__ W1, u16* __restrict__ w1t,
                            int* __restrict__ count) {
    int t = blockIdx.x * 256 + threadIdx.x;
    if (t == 0) *count = 0;
    if (t < 65536) {
        int n = t & 255, k = t >> 8;
        float w = W1[k * 256 + n];
        u16 h = f2bf(w);
        u16 l = f2bf(w - bf2f(h));
        int g = k >> 3, j = k & 7;
        w1t[n * 512 + g * 16 + j] = h;
        w1t[n * 512 + g * 16 + j + 8] = l;
    }
}

// ---- kernel 2: fused gather + split-bf16 32x32x16 MFMA + epilogue ----
// wave wv owns cols [wv*64, wv*64+64) as 2 n-tiles of 32; edges 64 = 2 m-tiles of 32.
// A[m=lane&31][k=8*(lane>>5)+j]; B[k][n=lane&31] mirrored;
// C/D: col=lane&31, row=(reg&3)+8*(reg>>2)+4*(lane>>5)   (m74/m101-verified).
// (256,3): cap 170 VGPR; R4 measured 100 arch + 64 acc = 164 unified -> fits, no spill.
// 12 waves/CU (vs R4's ~7.3) is the point: more outstanding scattered gather misses.
__global__ __launch_bounds__(THREADS, 3)
void linkmlp_mfma(const float* __restrict__ emb, const int* __restrict__ ei,
                  const u16* __restrict__ w1t, const float* __restrict__ b1,
                  const float* __restrict__ W2, const float* __restrict__ b2p,
                  float* __restrict__ out, int* __restrict__ count,
                  int* __restrict__ list, int cap, int E)
{
    __shared__ u16 x_hi[TE * XS];      // single-buffered x tile (hi/lo bf16)
    __shared__ u16 x_lo[TE * XS];
    __shared__ float red[4][TE];
    __shared__ int s_idx[2][TE];

    const int tid  = threadIdx.x;
    const int base = blockIdx.x * TE;
    const int lane = tid & 63;
    const int wv   = tid >> 6;
    const int l31  = lane & 31;
    const int q8   = lane >> 5;
    const int ge   = tid >> 5;    // gather: edge sub-index 0..7 (+8 per pass)
    const int gseg = tid & 31;    // gather: float4 segment within 512B row

    if (tid < TE) { int e = base + tid; s_idx[0][tid] = (e < E) ? ei[e] : 0; }
    else if (tid < 2 * TE) { int t2 = tid - TE; int e = base + t2; s_idx[1][t2] = (e < E) ? ei[E + e] : 0; }
    __syncthreads();

    float b1v[2], w2v[2];
    #pragma unroll
    for (int nt = 0; nt < 2; ++nt) {
        int c = wv * 64 + nt * 32 + l31;
        b1v[nt] = b1[c];
        w2v[nt] = W2[c];
    }
    const float b2s = b2p[0];

    f16v acc[2][2];
    #pragma unroll
    for (int mt = 0; mt < 2; ++mt)
        #pragma unroll
        for (int nt = 0; nt < 2; ++nt)
            acc[mt][nt] = (f16v)0.f;

    float4 gv[8];
    auto issue_gather = [&](int half) {        // 8 independent float4 loads (random rows)
        #pragma unroll
        for (int q = 0; q < 8; ++q) {
            int node = s_idx[half][ge + 8 * q];
            gv[q] = ((const float4*)(emb + (size_t)node * 128))[gseg];
        }
    };
    auto write_gather = [&]() {                // split fp32 -> bf16 hi/lo, ds_write_b64 x2
        #pragma unroll
        for (int q = 0; q < 8; ++q) {
            float4 v = gv[q];
            u16 h0 = f2bf(v.x), h1 = f2bf(v.y), h2 = f2bf(v.z), h3 = f2bf(v.w);
            u16 l0 = f2bf(v.x - bf2f(h0)), l1 = f2bf(v.y - bf2f(h1));
            u16 l2 = f2bf(v.z - bf2f(h2)), l3 = f2bf(v.w - bf2f(h3));
            int off = (ge + 8 * q) * XS + gseg * 4;
            *(uint2*)&x_hi[off] = make_uint2((unsigned)h0 | ((unsigned)h1 << 16),
                                             (unsigned)h2 | ((unsigned)h3 << 16));
            *(uint2*)&x_lo[off] = make_uint2((unsigned)l0 | ((unsigned)l1 << 16),
                                             (unsigned)l2 | ((unsigned)l3 << 16));
        }
    };

    // prologue: stage half 0
    issue_gather(0);
    write_gather();
    __syncthreads();

    #pragma unroll
    for (int half = 0; half < 2; ++half) {
        const int arow0 = l31 * XS;
        const int arow1 = (32 + l31) * XS;
        const u16* bbase0 = w1t + (size_t)(wv * 64 + l31) * 512 + (half * 16 + q8) * 16;
        const u16* bbase1 = bbase0 + 32 * 512;

        // prefetch next half's gather at the TOP of compute: ~8 ksteps (~3k cy) of cover
        if (half == 0) issue_gather(1);

        auto kstep = [&](int sl) {             // one K=16 step: 4 ds_read_b128 + 4 glb x4 + 12 MFMA
            const int aoff = 16 * sl + 8 * q8;
            s8v ah0 = *(const s8v*)&x_hi[arow0 + aoff];
            s8v ah1 = *(const s8v*)&x_hi[arow1 + aoff];
            s8v al0 = *(const s8v*)&x_lo[arow0 + aoff];
            s8v al1 = *(const s8v*)&x_lo[arow1 + aoff];
            const u16* bp0 = bbase0 + sl * 32;
            const u16* bp1 = bbase1 + sl * 32;
            s8v bh0 = *(const s8v*)bp0;  s8v bl0 = *(const s8v*)(bp0 + 8);
            s8v bh1 = *(const s8v*)bp1;  s8v bl1 = *(const s8v*)(bp1 + 8);
            // 3-term split: xh*wh + xh*wl + xl*wh (xl*wl ~2^-18, dropped)
            acc[0][0] = __builtin_amdgcn_mfma_f32_32x32x16_bf16(ah0, bh0, acc[0][0], 0, 0, 0);
            acc[0][0] = __builtin_amdgcn_mfma_f32_32x32x16_bf16(ah0, bl0, acc[0][0], 0, 0, 0);
            acc[0][0] = __builtin_amdgcn_mfma_f32_32x32x16_bf16(al0, bh0, acc[0][0], 0, 0, 0);
            acc[1][0] = __builtin_amdgcn_mfma_f32_32x32x16_bf16(ah1, bh0, acc[1][0], 0, 0, 0);
            acc[1][0] = __builtin_amdgcn_mfma_f32_32x32x16_bf16(ah1, bl0, acc[1][0], 0, 0, 0);
            acc[1][0] = __builtin_amdgcn_mfma_f32_32x32x16_bf16(al1, bh0, acc[1][0], 0, 0, 0);
            acc[0][1] = __builtin_amdgcn_mfma_f32_32x32x16_bf16(ah0, bh1, acc[0][1], 0, 0, 0);
            acc[0][1] = __builtin_amdgcn_mfma_f32_32x32x16_bf16(ah0, bl1, acc[0][1], 0, 0, 0);
            acc[0][1] = __builtin_amdgcn_mfma_f32_32x32x16_bf16(al0, bh1, acc[0][1], 0, 0, 0);
            acc[1][1] = __builtin_amdgcn_mfma_f32_32x32x16_bf16(ah1, bh1, acc[1][1], 0, 0, 0);
            acc[1][1] = __builtin_amdgcn_mfma_f32_32x32x16_bf16(ah1, bl1, acc[1][1], 0, 0, 0);
            acc[1][1] = __builtin_amdgcn_mfma_f32_32x32x16_bf16(al1, bh1, acc[1][1], 0, 0, 0);
        };

        kstep(0); kstep(1); kstep(2); kstep(3);
        kstep(4); kstep(5); kstep(6); kstep(7);

        if (half == 0) {
            __syncthreads();        // all reads of half-0 tile done
            write_gather();         // overwrite with half-1 tile
            __syncthreads();        // writes visible
        }
    }

    // epilogue: h=relu(acc+b1), partial = sum over this wave's 64 cols
    #pragma unroll
    for (int mt = 0; mt < 2; ++mt) {
        #pragma unroll
        for (int r = 0; r < 16; ++r) {
            float h0 = acc[mt][0][r] + b1v[0];
            float h1 = acc[mt][1][r] + b1v[1];
            float pp = (h0 > 0.f ? h0 : 0.f) * w2v[0] + (h1 > 0.f ? h1 : 0.f) * w2v[1];
            pp += __shfl_xor(pp, 1);  pp += __shfl_xor(pp, 2);
            pp += __shfl_xor(pp, 4);  pp += __shfl_xor(pp, 8);
            pp += __shfl_xor(pp, 16);
            if (l31 == 0)
                red[wv][mt * 32 + (r & 3) + 8 * (r >> 2) + 4 * q8] = pp;
        }
    }
    __syncthreads();

    if (tid < TE) {
        int eg = base + tid;
        if (eg < E) {
            float raw = red[0][tid] + red[1][tid] + red[2][tid] + red[3][tid] + b2s;
            out[eg] = (raw < T_SM) ? 0.f : raw;
            if (fabsf(raw - T_SM) < NEAR_MARGIN) {   // near-threshold -> exact recompute
                int pos = atomicAdd(count, 1);
                if (pos < cap) list[pos] = eg;
            }
        }
    }
}

// ---- kernel 3: exact fp32 recompute of near-threshold edges (one wave/edge) ----
__global__ __launch_bounds__(256, 4)
void fixup_kernel(const float* __restrict__ emb, const int* __restrict__ ei,
                  const float* __restrict__ W1, const float* __restrict__ b1,
                  const float* __restrict__ W2, const float* __restrict__ b2p,
                  const int* __restrict__ count, const int* __restrict__ list,
                  float* __restrict__ out, int E, int cap)
{
    int cnt = *count; if (cnt > cap) cnt = cap;
    const int lane = threadIdx.x & 63;
    const int gw = (blockIdx.x * 256 + threadIdx.x) >> 6;
    const int nw = (gridDim.x * 256) >> 6;
    for (int i = gw; i < cnt; i += nw) {
        int e = list[i];
        int rn = ei[e], cn = ei[E + e];
        const float* src = (lane < 32) ? emb + (size_t)rn * 128 + lane * 4
                                       : emb + (size_t)cn * 128 + (lane - 32) * 4;
        float4 xv = *(const float4*)src;
        float hacc[4] = {0.f, 0.f, 0.f, 0.f};
        for (int k0 = 0; k0 < 256; k0 += 4) {
            int sl = k0 >> 2;
            float x0 = __shfl(xv.x, sl), x1 = __shfl(xv.y, sl);
            float x2 = __shfl(xv.z, sl), x3 = __shfl(xv.w, sl);
            #pragma unroll
            for (int c = 0; c < 4; ++c) {
                int col = lane + 64 * c;
                hacc[c] += x0 * W1[(k0 + 0) * 256 + col] + x1 * W1[(k0 + 1) * 256 + col]
                         + x2 * W1[(k0 + 2) * 256 + col] + x3 * W1[(k0 + 3) * 256 + col];
            }
        }
        float p = 0.f;
        #pragma unroll
        for (int c = 0; c < 4; ++c) {
            float h = hacc[c] + b1[lane + 64 * c];
            p += (h > 0.f ? h : 0.f) * W2[lane + 64 * c];
        }
        p += __shfl_xor(p, 1);  p += __shfl_xor(p, 2);  p += __shfl_xor(p, 4);
        p += __shfl_xor(p, 8);  p += __shfl_xor(p, 16); p += __shfl_xor(p, 32);
        if (lane == 0) {
            float raw = p + b2p[0];
            out[e] = (raw < T_SM) ? 0.f : raw;
        }
    }
}

extern "C" void kernel_launch(void* const* d_in, const int* in_sizes, int n_in,
                              void* d_out, int out_size, void* d_ws, size_t ws_size,
                              hipStream_t stream) {
    const float* emb = (const float*)d_in[0];
    const int*   ei  = (const int*)  d_in[1];
    const float* W1  = (const float*)d_in[2];
    const float* b1  = (const float*)d_in[3];
    const float* W2  = (const float*)d_in[4];
    const float* b2  = (const float*)d_in[5];
    float* out = (float*)d_out;
    const int E = out_size;

    // ws layout: [0,256KB) w1t ; [256KB] count ; [256KB+64 ..) fixup list
    u16* w1t   = (u16*)d_ws;
    int* count = (int*)((char*)d_ws + 262144);
    int* list  = (int*)((char*)d_ws + 262208);
    long avail = (long)ws_size - 262208;
    int cap = (avail > 4) ? (int)(avail / 4) : 0;
    if (cap > E) cap = E;

    hipLaunchKernelGGL(prep_kernel, dim3(256), dim3(256), 0, stream, W1, w1t, count);
    hipLaunchKernelGGL(linkmlp_mfma, dim3((E + TE - 1) / TE), dim3(THREADS), 0, stream,
                       emb, ei, w1t, b1, W2, b2, out, count, list, cap, E);
    hipLaunchKernelGGL(fixup_kernel, dim3(128), dim3(256), 0, stream,
                       emb, ei, W1, b1, W2, b2, count, list, out, E, cap);
}

// Round 6
// 331.052 us; speedup vs baseline: 1.7239x; 1.4343x over previous
//
#include <hip/hip_runtime.h>

#define TE 64
#define THREADS 256
#define XS 136         // u16 LDS stride per row: 128 + 8 pad (conflict-free)
#define T_SM 0.05f
#define MARGIN_FAST 5e-3f   // fp16-Y raw err ~5sigma = 1.7e-3 << margin
#define MARGIN_FB   1e-3f

typedef short s8v __attribute__((ext_vector_type(8)));    // 8 bf16 = 4 VGPRs (MFMA A/B frag)
typedef float f16v __attribute__((ext_vector_type(16)));  // 32x32 C/D frag
typedef unsigned short u16;

__device__ __forceinline__ u16 f2bf(float x) {            // fp32 -> bf16 RNE
    union { float f; unsigned u; } v; v.f = x;
    return (u16)((v.u + 0x7FFFu + ((v.u >> 16) & 1u)) >> 16);
}
__device__ __forceinline__ float bf2f(u16 h) {
    union { unsigned u; float f; } v; v.u = ((unsigned)h) << 16;
    return v.f;
}

// ---- W1 [256,256] f32 -> bf16 hi/lo in B-fragment layout; also zero count ----
// col n, k-group g=k/8 in [0,32): w1t[n*512 + g*16 + j]=hi, [+8]=lo.
__global__ void prep_kernel(const float* __restrict__ W1, u16* __restrict__ w1t,
                            int* __restrict__ count) {
    int t = blockIdx.x * 256 + threadIdx.x;
    if (t == 0) *count = 0;
    if (t < 65536) {
        int n = t & 255, k = t >> 8;
        float w = W1[k * 256 + n];
        u16 h = f2bf(w);
        u16 l = f2bf(w - bf2f(h));
        int g = k >> 3, j = k & 7;
        w1t[n * 512 + g * 16 + j] = h;
        w1t[n * 512 + g * 16 + j + 8] = l;
    }
}

// ============================ FAST PATH ============================
// Dense GEMM: Y[n][0:256]=emb[n]@W1[0:128,:] (g 0..15), Y[n][256:512]=emb[n]@W1[128:,:] (g 16..31).
// Per block: 64 sequential nodes; wave wv owns out-cols [wv*128, wv*128+128) = 4 n-tiles of 32.
// Frag layouts (m74/m101-verified): A[m=lane&31][k=8*(lane>>5)+j]; C/D col=lane&31,
// row=(reg&3)+8*(reg>>2)+4*(lane>>5).
__global__ __launch_bounds__(THREADS, 2)   // acc 128 + operands: needs the 256-VGPR budget
void gemm_y_kernel(const float* __restrict__ emb, const u16* __restrict__ w1t,
                   _Float16* __restrict__ Y, int Nn)
{
    __shared__ u16 x_hi[TE * XS];
    __shared__ u16 x_lo[TE * XS];

    const int tid  = threadIdx.x;
    const int base = blockIdx.x * TE;
    const int lane = tid & 63;
    const int wv   = tid >> 6;
    const int l31  = lane & 31;
    const int q8   = lane >> 5;
    const int ge   = tid >> 5;
    const int gseg = tid & 31;

    // stage 64 sequential emb rows (coalesced), split to bf16 hi/lo
    #pragma unroll
    for (int q = 0; q < 8; ++q) {
        int node = base + ge + 8 * q;
        if (node >= Nn) node = Nn - 1;
        float4 v = ((const float4*)(emb + (size_t)node * 128))[gseg];
        u16 h0 = f2bf(v.x), h1 = f2bf(v.y), h2 = f2bf(v.z), h3 = f2bf(v.w);
        u16 l0 = f2bf(v.x - bf2f(h0)), l1 = f2bf(v.y - bf2f(h1));
        u16 l2 = f2bf(v.z - bf2f(h2)), l3 = f2bf(v.w - bf2f(h3));
        int off = (ge + 8 * q) * XS + gseg * 4;
        *(uint2*)&x_hi[off] = make_uint2((unsigned)h0 | ((unsigned)h1 << 16),
                                         (unsigned)h2 | ((unsigned)h3 << 16));
        *(uint2*)&x_lo[off] = make_uint2((unsigned)l0 | ((unsigned)l1 << 16),
                                         (unsigned)l2 | ((unsigned)l3 << 16));
    }
    __syncthreads();

    f16v acc[2][4];
    #pragma unroll
    for (int mt = 0; mt < 2; ++mt)
        #pragma unroll
        for (int nt = 0; nt < 4; ++nt)
            acc[mt][nt] = (f16v)0.f;

    const int arow0 = l31 * XS;
    const int arow1 = (32 + l31) * XS;
    const u16* bb[4];
    #pragma unroll
    for (int nt = 0; nt < 4; ++nt) {
        int ncol = wv * 128 + nt * 32 + l31;          // 0..511
        int p = ncol & 255;
        int gbase = (ncol >> 8) * 16;                 // Yr: g0..15, Yc: g16..31
        bb[nt] = w1t + (size_t)p * 512 + (gbase + q8) * 16;
    }

    #pragma unroll
    for (int sl = 0; sl < 8; ++sl) {                  // K=128 in 8 ksteps of 16
        const int aoff = 16 * sl + 8 * q8;
        s8v ah0 = *(const s8v*)&x_hi[arow0 + aoff];
        s8v ah1 = *(const s8v*)&x_hi[arow1 + aoff];
        s8v al0 = *(const s8v*)&x_lo[arow0 + aoff];
        s8v al1 = *(const s8v*)&x_lo[arow1 + aoff];
        #pragma unroll
        for (int nt = 0; nt < 4; ++nt) {
            const u16* bp = bb[nt] + sl * 32;
            s8v bh = *(const s8v*)bp;
            s8v bl = *(const s8v*)(bp + 8);
            acc[0][nt] = __builtin_amdgcn_mfma_f32_32x32x16_bf16(ah0, bh, acc[0][nt], 0, 0, 0);
            acc[0][nt] = __builtin_amdgcn_mfma_f32_32x32x16_bf16(ah0, bl, acc[0][nt], 0, 0, 0);
            acc[0][nt] = __builtin_amdgcn_mfma_f32_32x32x16_bf16(al0, bh, acc[0][nt], 0, 0, 0);
            acc[1][nt] = __builtin_amdgcn_mfma_f32_32x32x16_bf16(ah1, bh, acc[1][nt], 0, 0, 0);
            acc[1][nt] = __builtin_amdgcn_mfma_f32_32x32x16_bf16(ah1, bl, acc[1][nt], 0, 0, 0);
            acc[1][nt] = __builtin_amdgcn_mfma_f32_32x32x16_bf16(al1, bh, acc[1][nt], 0, 0, 0);
        }
    }

    // store fp16: lanes l31=0..31 cover 32 consecutive cols -> 64B-contiguous per store group
    #pragma unroll
    for (int mt = 0; mt < 2; ++mt) {
        #pragma unroll
        for (int r = 0; r < 16; ++r) {
            int node = base + mt * 32 + (r & 3) + 8 * (r >> 2) + 4 * q8;
            if (node < Nn) {
                _Float16* yp = Y + (size_t)node * 512 + wv * 128 + l31;
                #pragma unroll
                for (int nt = 0; nt < 4; ++nt)
                    yp[nt * 32] = (_Float16)acc[mt][nt][r];
            }
        }
    }
}

// Edge pass: raw(e) = relu(Yr[row]+Yc[col]+b1) . W2 + b2. Half-wave per edge:
// lane covers 8 of 256 h-cols; 2x 16B loads from the L3-resident Y table.
__global__ __launch_bounds__(256, 6)
void edge_kernel(const _Float16* __restrict__ Y, const int* __restrict__ ei,
                 const float* __restrict__ b1, const float* __restrict__ W2,
                 const float* __restrict__ b2p, float* __restrict__ out,
                 int* __restrict__ count, int* __restrict__ list, int cap, int E)
{
    const int tid = threadIdx.x;
    const int l31 = tid & 31;
    const int q8  = (tid & 63) >> 5;
    const int gw  = (blockIdx.x * 256 + tid) >> 6;
    const int nw  = (gridDim.x * 256) >> 6;

    float b1v[8], w2v[8];
    #pragma unroll
    for (int j = 0; j < 8; ++j) {
        b1v[j] = b1[8 * l31 + j];
        w2v[j] = W2[8 * l31 + j];
    }
    const float b2s = b2p[0];
    const int npairs = (E + 1) >> 1;

    for (int pair = gw; pair < npairs; pair += nw) {
        int e = 2 * pair + q8;
        bool valid = e < E;
        int es = valid ? e : 0;
        int row = ei[es], col = ei[E + es];       // same addr across half-wave: broadcast
        union { uint4 u; _Float16 h[8]; } yr, yc;
        yr.u = *(const uint4*)(Y + (size_t)row * 512 + 8 * l31);
        yc.u = *(const uint4*)(Y + (size_t)col * 512 + 256 + 8 * l31);
        float p = 0.f;
        #pragma unroll
        for (int j = 0; j < 8; ++j) {
            float h = (float)yr.h[j] + (float)yc.h[j] + b1v[j];
            p += (h > 0.f ? h : 0.f) * w2v[j];
        }
        p += __shfl_xor(p, 1);  p += __shfl_xor(p, 2);  p += __shfl_xor(p, 4);
        p += __shfl_xor(p, 8);  p += __shfl_xor(p, 16);   // stays within 32-lane half
        if (l31 == 0 && valid) {
            float raw = p + b2s;
            out[e] = (raw < T_SM) ? 0.f : raw;
            if (fabsf(raw - T_SM) < MARGIN_FAST) {
                int pos = atomicAdd(count, 1);
                if (pos < cap) list[pos] = e;
            }
        }
    }
}

// ============================ FALLBACK PATH (R5, proven 475 us) ============================
__global__ __launch_bounds__(THREADS, 3)
void linkmlp_mfma(const float* __restrict__ emb, const int* __restrict__ ei,
                  const u16* __restrict__ w1t, const float* __restrict__ b1,
                  const float* __restrict__ W2, const float* __restrict__ b2p,
                  float* __restrict__ out, int* __restrict__ count,
                  int* __restrict__ list, int cap, int E)
{
    __shared__ u16 x_hi[TE * XS];
    __shared__ u16 x_lo[TE * XS];
    __shared__ float red[4][TE];
    __shared__ int s_idx[2][TE];

    const int tid  = threadIdx.x;
    const int base = blockIdx.x * TE;
    const int lane = tid & 63;
    const int wv   = tid >> 6;
    const int l31  = lane & 31;
    const int q8   = lane >> 5;
    const int ge   = tid >> 5;
    const int gseg = tid & 31;

    if (tid < TE) { int e = base + tid; s_idx[0][tid] = (e < E) ? ei[e] : 0; }
    else if (tid < 2 * TE) { int t2 = tid - TE; int e = base + t2; s_idx[1][t2] = (e < E) ? ei[E + e] : 0; }
    __syncthreads();

    float b1v[2], w2v[2];
    #pragma unroll
    for (int nt = 0; nt < 2; ++nt) {
        int c = wv * 64 + nt * 32 + l31;
        b1v[nt] = b1[c];
        w2v[nt] = W2[c];
    }
    const float b2s = b2p[0];

    f16v acc[2][2];
    #pragma unroll
    for (int mt = 0; mt < 2; ++mt)
        #pragma unroll
        for (int nt = 0; nt < 2; ++nt)
            acc[mt][nt] = (f16v)0.f;

    float4 gv[8];
    auto issue_gather = [&](int half) {
        #pragma unroll
        for (int q = 0; q < 8; ++q) {
            int node = s_idx[half][ge + 8 * q];
            gv[q] = ((const float4*)(emb + (size_t)node * 128))[gseg];
        }
    };
    auto write_gather = [&]() {
        #pragma unroll
        for (int q = 0; q < 8; ++q) {
            float4 v = gv[q];
            u16 h0 = f2bf(v.x), h1 = f2bf(v.y), h2 = f2bf(v.z), h3 = f2bf(v.w);
            u16 l0 = f2bf(v.x - bf2f(h0)), l1 = f2bf(v.y - bf2f(h1));
            u16 l2 = f2bf(v.z - bf2f(h2)), l3 = f2bf(v.w - bf2f(h3));
            int off = (ge + 8 * q) * XS + gseg * 4;
            *(uint2*)&x_hi[off] = make_uint2((unsigned)h0 | ((unsigned)h1 << 16),
                                             (unsigned)h2 | ((unsigned)h3 << 16));
            *(uint2*)&x_lo[off] = make_uint2((unsigned)l0 | ((unsigned)l1 << 16),
                                             (unsigned)l2 | ((unsigned)l3 << 16));
        }
    };

    issue_gather(0);
    write_gather();
    __syncthreads();

    #pragma unroll
    for (int half = 0; half < 2; ++half) {
        const int arow0 = l31 * XS;
        const int arow1 = (32 + l31) * XS;
        const u16* bbase0 = w1t + (size_t)(wv * 64 + l31) * 512 + (half * 16 + q8) * 16;
        const u16* bbase1 = bbase0 + 32 * 512;
        if (half == 0) issue_gather(1);

        auto kstep = [&](int sl) {
            const int aoff = 16 * sl + 8 * q8;
            s8v ah0 = *(const s8v*)&x_hi[arow0 + aoff];
            s8v ah1 = *(const s8v*)&x_hi[arow1 + aoff];
            s8v al0 = *(const s8v*)&x_lo[arow0 + aoff];
            s8v al1 = *(const s8v*)&x_lo[arow1 + aoff];
            const u16* bp0 = bbase0 + sl * 32;
            const u16* bp1 = bbase1 + sl * 32;
            s8v bh0 = *(const s8v*)bp0;  s8v bl0 = *(const s8v*)(bp0 + 8);
            s8v bh1 = *(const s8v*)bp1;  s8v bl1 = *(const s8v*)(bp1 + 8);
            acc[0][0] = __builtin_amdgcn_mfma_f32_32x32x16_bf16(ah0, bh0, acc[0][0], 0, 0, 0);
            acc[0][0] = __builtin_amdgcn_mfma_f32_32x32x16_bf16(ah0, bl0, acc[0][0], 0, 0, 0);
            acc[0][0] = __builtin_amdgcn_mfma_f32_32x32x16_bf16(al0, bh0, acc[0][0], 0, 0, 0);
            acc[1][0] = __builtin_amdgcn_mfma_f32_32x32x16_bf16(ah1, bh0, acc[1][0], 0, 0, 0);
            acc[1][0] = __builtin_amdgcn_mfma_f32_32x32x16_bf16(ah1, bl0, acc[1][0], 0, 0, 0);
            acc[1][0] = __builtin_amdgcn_mfma_f32_32x32x16_bf16(al1, bh0, acc[1][0], 0, 0, 0);
            acc[0][1] = __builtin_amdgcn_mfma_f32_32x32x16_bf16(ah0, bh1, acc[0][1], 0, 0, 0);
            acc[0][1] = __builtin_amdgcn_mfma_f32_32x32x16_bf16(ah0, bl1, acc[0][1], 0, 0, 0);
            acc[0][1] = __builtin_amdgcn_mfma_f32_32x32x16_bf16(al0, bh1, acc[0][1], 0, 0, 0);
            acc[1][1] = __builtin_amdgcn_mfma_f32_32x32x16_bf16(ah1, bh1, acc[1][1], 0, 0, 0);
            acc[1][1] = __builtin_amdgcn_mfma_f32_32x32x16_bf16(ah1, bl1, acc[1][1], 0, 0, 0);
            acc[1][1] = __builtin_amdgcn_mfma_f32_32x32x16_bf16(al1, bh1, acc[1][1], 0, 0, 0);
        };

        kstep(0); kstep(1); kstep(2); kstep(3);
        kstep(4); kstep(5); kstep(6); kstep(7);

        if (half == 0) {
            __syncthreads();
            write_gather();
            __syncthreads();
        }
    }

    #pragma unroll
    for (int mt = 0; mt < 2; ++mt) {
        #pragma unroll
        for (int r = 0; r < 16; ++r) {
            float h0 = acc[mt][0][r] + b1v[0];
            float h1 = acc[mt][1][r] + b1v[1];
            float pp = (h0 > 0.f ? h0 : 0.f) * w2v[0] + (h1 > 0.f ? h1 : 0.f) * w2v[1];
            pp += __shfl_xor(pp, 1);  pp += __shfl_xor(pp, 2);
            pp += __shfl_xor(pp, 4);  pp += __shfl_xor(pp, 8);
            pp += __shfl_xor(pp, 16);
            if (l31 == 0)
                red[wv][mt * 32 + (r & 3) + 8 * (r >> 2) + 4 * q8] = pp;
        }
    }
    __syncthreads();

    if (tid < TE) {
        int eg = base + tid;
        if (eg < E) {
            float raw = red[0][tid] + red[1][tid] + red[2][tid] + red[3][tid] + b2s;
            out[eg] = (raw < T_SM) ? 0.f : raw;
            if (fabsf(raw - T_SM) < MARGIN_FB) {
                int pos = atomicAdd(count, 1);
                if (pos < cap) list[pos] = eg;
            }
        }
    }
}

// ---- exact fp32 recompute of near-threshold edges (one wave/edge) ----
__global__ __launch_bounds__(256, 4)
void fixup_kernel(const float* __restrict__ emb, const int* __restrict__ ei,
                  const float* __restrict__ W1, const float* __restrict__ b1,
                  const float* __restrict__ W2, const float* __restrict__ b2p,
                  const int* __restrict__ count, const int* __restrict__ list,
                  float* __restrict__ out, int E, int cap)
{
    int cnt = *count; if (cnt > cap) cnt = cap;
    const int lane = threadIdx.x & 63;
    const int gw = (blockIdx.x * 256 + threadIdx.x) >> 6;
    const int nw = (gridDim.x * 256) >> 6;
    for (int i = gw; i < cnt; i += nw) {
        int e = list[i];
        int rn = ei[e], cn = ei[E + e];
        const float* src = (lane < 32) ? emb + (size_t)rn * 128 + lane * 4
                                       : emb + (size_t)cn * 128 + (lane - 32) * 4;
        float4 xv = *(const float4*)src;
        float hacc[4] = {0.f, 0.f, 0.f, 0.f};
        for (int k0 = 0; k0 < 256; k0 += 4) {
            int sl = k0 >> 2;
            float x0 = __shfl(xv.x, sl), x1 = __shfl(xv.y, sl);
            float x2 = __shfl(xv.z, sl), x3 = __shfl(xv.w, sl);
            #pragma unroll
            for (int c = 0; c < 4; ++c) {
                int col = lane + 64 * c;
                hacc[c] += x0 * W1[(k0 + 0) * 256 + col] + x1 * W1[(k0 + 1) * 256 + col]
                         + x2 * W1[(k0 + 2) * 256 + col] + x3 * W1[(k0 + 3) * 256 + col];
            }
        }
        float p = 0.f;
        #pragma unroll
        for (int c = 0; c < 4; ++c) {
            float h = hacc[c] + b1[lane + 64 * c];
            p += (h > 0.f ? h : 0.f) * W2[lane + 64 * c];
        }
        p += __shfl_xor(p, 1);  p += __shfl_xor(p, 2);  p += __shfl_xor(p, 4);
        p += __shfl_xor(p, 8);  p += __shfl_xor(p, 16); p += __shfl_xor(p, 32);
        if (lane == 0) {
            float raw = p + b2p[0];
            out[e] = (raw < T_SM) ? 0.f : raw;
        }
    }
}

extern "C" void kernel_launch(void* const* d_in, const int* in_sizes, int n_in,
                              void* d_out, int out_size, void* d_ws, size_t ws_size,
                              hipStream_t stream) {
    const float* emb = (const float*)d_in[0];
    const int*   ei  = (const int*)  d_in[1];
    const float* W1  = (const float*)d_in[2];
    const float* b1  = (const float*)d_in[3];
    const float* W2  = (const float*)d_in[4];
    const float* b2  = (const float*)d_in[5];
    float* out = (float*)d_out;
    const int E  = out_size;
    const int Nn = in_sizes[0] / 128;

    const size_t yBytes = (size_t)Nn * 512 * sizeof(_Float16);   // 102.4 MB @ N=100000
    const size_t fastNeed = yBytes + 262144 + 64 + 65536;

    if (ws_size >= fastNeed) {
        // fast path: factorized Y-table
        _Float16* Y = (_Float16*)d_ws;
        u16* w1t   = (u16*)((char*)d_ws + yBytes);
        int* count = (int*)((char*)d_ws + yBytes + 262144);
        int* list  = (int*)((char*)d_ws + yBytes + 262208);
        int cap = (int)((ws_size - (yBytes + 262208)) / 4);
        if (cap > E) cap = E;

        hipLaunchKernelGGL(prep_kernel, dim3(256), dim3(256), 0, stream, W1, w1t, count);
        hipLaunchKernelGGL(gemm_y_kernel, dim3((Nn + TE - 1) / TE), dim3(THREADS), 0, stream,
                           emb, w1t, Y, Nn);
        hipLaunchKernelGGL(edge_kernel, dim3(4096), dim3(256), 0, stream,
                           Y, ei, b1, W2, b2, out, count, list, cap, E);
        hipLaunchKernelGGL(fixup_kernel, dim3(512), dim3(256), 0, stream,
                           emb, ei, W1, b1, W2, b2, count, list, out, E, cap);
    } else {
        // fallback: R5 fused edge-GEMM (proven)
        u16* w1t   = (u16*)d_ws;
        int* count = (int*)((char*)d_ws + 262144);
        int* list  = (int*)((char*)d_ws + 262208);
        long avail = (long)ws_size - 262208;
        int cap = (avail > 4) ? (int)(avail / 4) : 0;
        if (cap > E) cap = E;

        hipLaunchKernelGGL(prep_kernel, dim3(256), dim3(256), 0, stream, W1, w1t, count);
        hipLaunchKernelGGL(linkmlp_mfma, dim3((E + TE - 1) / TE), dim3(THREADS), 0, stream,
                           emb, ei, w1t, b1, W2, b2, out, count, list, cap, E);
        hipLaunchKernelGGL(fixup_kernel, dim3(128), dim3(256), 0, stream,
                           emb, ei, W1, b1, W2, b2, count, list, out, E, cap);
    }
}